// Round 1
// baseline (165.649 us; speedup 1.0000x reference)
//
#include <hip/hip_runtime.h>

#define HW 9216
#define CDIM 128
#define WIDTH 96
#define BATCH 2

typedef _Float16 half8 __attribute__((ext_vector_type(8)));
typedef float float4v __attribute__((ext_vector_type(4)));

// 1 / (sqrt(128) * 0.1)
#define INV_SCALE 0.8838834764831844f

// ---------------------------------------------------------------------------
// Kernel 1: L2-normalize over channel dim, write fp16 in [B][HW][C] layout
// ---------------------------------------------------------------------------
__global__ __launch_bounds__(256) void norm_kernel(const float* __restrict__ fL,
                                                   const float* __restrict__ fR,
                                                   _Float16* __restrict__ Qh,
                                                   _Float16* __restrict__ Kh)
{
    const float* src = (blockIdx.y == 0) ? fL : fR;
    _Float16* dst    = (blockIdx.y == 0) ? Qh : Kh;
    int tid = blockIdx.x * 256 + threadIdx.x;   // 0 .. B*HW-1 (grid sized exactly)
    int b = tid / HW, pos = tid % HW;
    const float* p = src + (size_t)b * CDIM * HW + pos;

    float ss = 0.f;
    #pragma unroll 8
    for (int c = 0; c < CDIM; ++c) { float v = p[(size_t)c * HW]; ss += v * v; }
    float scale = 1.0f / fmaxf(sqrtf(ss), 1e-6f);

    _Float16* o = dst + (size_t)tid * CDIM;
    #pragma unroll
    for (int c8 = 0; c8 < CDIM / 8; ++c8) {
        _Float16 tmp[8];
        #pragma unroll
        for (int j = 0; j < 8; ++j)
            tmp[j] = (_Float16)(p[(size_t)(c8 * 8 + j) * HW] * scale);
        *(uint4*)(o + c8 * 8) = *(const uint4*)tmp;
    }
}

// ---------------------------------------------------------------------------
// Kernel 2: fused correlation + softmax-accumulate.
// Block: 128 q-rows x 128 keys S-tile, 4 waves each computing 64x64.
// Grid: (72 q-tiles, 8 key-splits, 2 batches). Each block sweeps 9 K-tiles.
// No online max needed: |logit| <= 0.884, exp in [0.41, 2.42].
// ---------------------------------------------------------------------------
__global__ __launch_bounds__(256, 2) void attn_kernel(const _Float16* __restrict__ Qh,
                                                      const _Float16* __restrict__ Kh,
                                                      float4* __restrict__ part)
{
    // +8 halves pad per row: row stride 272 B = 68 words -> 4-bank advance/row,
    // 2-way conflicts only (free per m136)
    __shared__ _Float16 Qs[128 * 136];
    __shared__ _Float16 Ks[128 * 136];

    const int qt = blockIdx.x, split = blockIdx.y, b = blockIdx.z;
    const int t = threadIdx.x;
    const int lane = t & 63, wave = t >> 6;
    const int wq = wave >> 1, wk = wave & 1;          // 2x2 wave grid over 128x128
    const int lane15 = lane & 15, quad = lane >> 4;

    // ---- stage Q tile (32 KB, contiguous in global) ----
    {
        const uint4* qg = (const uint4*)(Qh + ((size_t)(b * HW + qt * 128)) * CDIM);
        #pragma unroll
        for (int i = 0; i < 8; ++i) {
            int idx = i * 256 + t;
            int row = idx >> 4, col = (idx & 15) * 8;
            *(uint4*)&Qs[row * 136 + col] = qg[idx];
        }
    }

    float l[16], ax[16], ay[16], mx[16];
    #pragma unroll
    for (int s = 0; s < 16; ++s) { l[s] = 0.f; ax[s] = 0.f; ay[s] = 0.f; mx[s] = 0.f; }

    const int qrow0 = wq * 64;

    for (int kt = 0; kt < 9; ++kt) {
        const int kbase = split * 1152 + kt * 128;
        __syncthreads();   // protect Ks from previous iteration's readers
        {
            const uint4* kg = (const uint4*)(Kh + ((size_t)(b * HW + kbase)) * CDIM);
            #pragma unroll
            for (int i = 0; i < 8; ++i) {
                int idx = i * 256 + t;
                int row = idx >> 4, col = (idx & 15) * 8;
                *(uint4*)&Ks[row * 136 + col] = kg[idx];
            }
        }
        __syncthreads();

        float4v acc[4][4];
        #pragma unroll
        for (int mt = 0; mt < 4; ++mt)
            #pragma unroll
            for (int nt = 0; nt < 4; ++nt)
                acc[mt][nt] = (float4v)0.f;

        #pragma unroll
        for (int kc = 0; kc < 4; ++kc) {
            const int coff = kc * 32 + quad * 8;
            half8 af[4], bf[4];
            #pragma unroll
            for (int mt = 0; mt < 4; ++mt)
                af[mt] = *(const half8*)&Qs[(qrow0 + mt * 16 + lane15) * 136 + coff];
            #pragma unroll
            for (int nt = 0; nt < 4; ++nt)
                bf[nt] = *(const half8*)&Ks[(wk * 64 + nt * 16 + lane15) * 136 + coff];
            #pragma unroll
            for (int mt = 0; mt < 4; ++mt)
                #pragma unroll
                for (int nt = 0; nt < 4; ++nt)
                    acc[mt][nt] = __builtin_amdgcn_mfma_f32_16x16x32_f16(
                        af[mt], bf[nt], acc[mt][nt], 0, 0, 0);
        }

        // ---- fused softmax-accumulate epilogue for this K-tile ----
        #pragma unroll
        for (int nt = 0; nt < 4; ++nt) {
            int kpos = kbase + wk * 64 + nt * 16 + lane15;   // C/D col = lane&15
            float xf = (float)(kpos % WIDTH);
            float yf = (float)(kpos / WIDTH);
            #pragma unroll
            for (int mt = 0; mt < 4; ++mt) {
                #pragma unroll
                for (int r = 0; r < 4; ++r) {               // C/D row = quad*4 + r
                    float e = __expf(acc[mt][nt][r] * INV_SCALE);
                    int s = mt * 4 + r;
                    l[s] += e;
                    ax[s] += e * xf;
                    ay[s] += e * yf;
                    mx[s] = fmaxf(mx[s], e);
                }
            }
        }
    }

    // reduce over the 16 columns (lanes sharing a quad)
    #pragma unroll
    for (int s = 0; s < 16; ++s) {
        #pragma unroll
        for (int m = 1; m < 16; m <<= 1) {
            l[s]  += __shfl_xor(l[s],  m, 64);
            ax[s] += __shfl_xor(ax[s], m, 64);
            ay[s] += __shfl_xor(ay[s], m, 64);
            mx[s]  = fmaxf(mx[s], __shfl_xor(mx[s], m, 64));
        }
    }

    if (lane15 == 0) {
        #pragma unroll
        for (int mt = 0; mt < 4; ++mt) {
            #pragma unroll
            for (int r = 0; r < 4; ++r) {
                int row = qrow0 + mt * 16 + quad * 4 + r;
                int s = mt * 4 + r;
                part[((size_t)(b * HW + qt * 128 + row)) * 16 + split * 2 + wk] =
                    make_float4(l[s], ax[s], ay[s], mx[s]);
            }
        }
    }
}

// ---------------------------------------------------------------------------
// Kernel 3: combine 16 partials per query row, write flow + conf
// ---------------------------------------------------------------------------
__global__ __launch_bounds__(256) void combine_kernel(const float4* __restrict__ part,
                                                      float* __restrict__ out)
{
    int tid = blockIdx.x * 256 + threadIdx.x;   // 0 .. B*HW-1 (grid sized exactly)
    int b = tid / HW, pos = tid % HW;
    float l = 0.f, ax = 0.f, ay = 0.f, mx = 0.f;
    #pragma unroll
    for (int s = 0; s < 16; ++s) {
        float4 v = part[(size_t)tid * 16 + s];
        l += v.x; ax += v.y; ay += v.z; mx = fmaxf(mx, v.w);
    }
    float inv = 1.0f / l;
    int x = pos % WIDTH, y = pos / WIDTH;
    out[(size_t)b * 2 * HW + pos]           = ax * inv - (float)x;
    out[(size_t)b * 2 * HW + HW + pos]      = ay * inv - (float)y;
    out[(size_t)BATCH * 2 * HW + (size_t)b * HW + pos] = mx * inv;
}

// ---------------------------------------------------------------------------
extern "C" void kernel_launch(void* const* d_in, const int* in_sizes, int n_in,
                              void* d_out, int out_size, void* d_ws, size_t ws_size,
                              hipStream_t stream)
{
    const float* fL = (const float*)d_in[0];
    const float* fR = (const float*)d_in[1];
    float* out = (float*)d_out;

    char* ws = (char*)d_ws;
    const size_t QH_BYTES = (size_t)BATCH * HW * CDIM * sizeof(_Float16);  // 4.72 MB
    _Float16* Qh  = (_Float16*)ws;
    _Float16* Kh  = (_Float16*)(ws + QH_BYTES);
    float4*   part = (float4*)(ws + 2 * QH_BYTES);                         // 4.72 MB

    norm_kernel<<<dim3((BATCH * HW) / 256, 2), 256, 0, stream>>>(fL, fR, Qh, Kh);
    attn_kernel<<<dim3(HW / 128, 8, BATCH), 256, 0, stream>>>(Qh, Kh, part);
    combine_kernel<<<dim3((BATCH * HW) / 256), 256, 0, stream>>>(part, out);
}